// Round 13
// baseline (82.674 us; speedup 1.0000x reference)
//
#include <hip/hip_runtime.h>
#include <hip/hip_bf16.h>

// DCNv2 fwd — R13: ABLATION ROUND (V0 real + V1 no-gather + V2 gather-only)
// plus V0 improvements: zero-padded 104x104 NHWC halo (no bounds masks, 1
// addr calc + const offsets per 4 corners), sched_barrier removed.
// B=8, C=64, H=W=96, O=64, K=3, s=1, p=1, d=1, DG=1 -> Ho=Wo=96.

#define B_   8
#define C_   64
#define H_   96
#define W_   96
#define O_   64
#define KK_  9
#define HW_  (H_ * W_)          // 9216
#define NTILE (HW_ / 64)        // 144
#define PW_  104                // padded width/height (halo: interior at +2)
#define PHW_ (PW_ * PW_)        // 10816

typedef __attribute__((ext_vector_type(8))) short short8;     // 8 bf16
typedef __attribute__((ext_vector_type(4))) float f32x4;
typedef __attribute__((ext_vector_type(4))) unsigned uint4v;

__device__ __forceinline__ unsigned short f2bf(float f) {
    union { float f; unsigned u; } v; v.f = f;
    unsigned r = v.u + 0x7FFF + ((v.u >> 16) & 1);   // RNE
    return (unsigned short)(r >> 16);
}
__device__ __forceinline__ float bflo(unsigned u) {
    union { unsigned u; float f; } v; v.u = u << 16; return v.f;
}
__device__ __forceinline__ float bfhi(unsigned u) {
    union { unsigned u; float f; } v; v.u = u & 0xffff0000u; return v.f;
}
__device__ __forceinline__ unsigned packbf2(float lo, float hi) {
    __hip_bfloat162 h = __float22bfloat162_rn(make_float2(lo, hi));
    union { __hip_bfloat162 h; unsigned u; } v; v.h = h; return v.u;
}

// ---- converter: x NCHW f32 -> PADDED NHWC bf16 (zeros halo);
//      blocks 0..15 also emit fragment-ordered bf16 weights ----
__global__ __launch_bounds__(256)
void cvt_kernel(const float* __restrict__ x, const float* __restrict__ wgt,
                unsigned short* __restrict__ xP, unsigned short* __restrict__ wsb)
{
    const int t = threadIdx.x;
    if (blockIdx.x < 16) {
        int i = blockIdx.x * 256 + t;      // (o,c) over 4096
        int o = i >> 6, c = i & 63;
        int ks = c >> 5, hi = (c >> 3) & 3, j = c & 7;
        #pragma unroll
        for (int kk = 0; kk < KK_; ++kk)
            wsb[(size_t)(((kk*2 + ks)*4 + hi)*64 + o)*8 + j] =
                f2bf(wgt[(size_t)(o*64 + c)*KK_ + kk]);
    }
    const int b = blockIdx.x & 7;                  // XCD-pinned
    const int p = (blockIdx.x >> 3) * 256 + t;     // padded pixel id
    if (p >= PHW_) return;
    const int py = p / PW_, px = p % PW_;
    const bool interior = (py >= 2) & (py < 2 + H_) & (px >= 2) & (px < 2 + W_);
    const int sp = (py - 2) * W_ + (px - 2);
    const float* xs = x + (size_t)b * C_ * HW_ + sp;
    unsigned pk[32];
    #pragma unroll
    for (int c2 = 0; c2 < 32; ++c2)
        pk[c2] = interior ? packbf2(xs[(size_t)(2*c2) * HW_],
                                    xs[(size_t)(2*c2+1) * HW_]) : 0u;
    uint4v* dst = (uint4v*)(xP + ((size_t)b * PHW_ + p) * C_);
    #pragma unroll
    for (int j = 0; j < 8; ++j) {
        uint4v v;
        v.x = pk[4*j]; v.y = pk[4*j+1]; v.z = pk[4*j+2]; v.w = pk[4*j+3];
        dst[j] = v;
    }
}

// LDS: stg 4 waves x 2048 B | wl dbuf 2 x 8192 B | epilogue alias [64][68] f32
// V=0: real kernel (writes out). V=1: no corner loads. V=2: loads only.
template<int V>
__global__ __launch_bounds__(256, 4)
void dcn_mfma(const unsigned short* __restrict__ xP,
              const float* __restrict__ offs, const float* __restrict__ mask,
              const unsigned short* __restrict__ wsb,
              const float* __restrict__ bias, float* __restrict__ out)
{
    __shared__ __align__(16) char lds[24576];
    char* stg = lds + (threadIdx.x >> 6) * 2048;
    char* wl0 = lds + 8192;

    const int t    = threadIdx.x;
    const int lane = t & 63;
    const int wid  = t >> 6;
    const int bi   = blockIdx.x & 7;               // XCD-pinned
    const int tile = blockIdx.x >> 3;
    const int pixbase = tile * 64;

    const int lr = lane & 15, lg = lane >> 4;      // MFMA fragment coords
    const int s   = lane & 7;                      // 16B slice within line
    const int ph0 = lane >> 3;                     // pixel (h=0); h=1 adds 8
    const int pix0 = pixbase + wid * 16 + ph0;

    const float* offB = offs + (size_t)bi * 18 * HW_;
    const float* mB   = mask + (size_t)bi * 9  * HW_;
    const unsigned short* xB = xP + (size_t)bi * PHW_ * C_ + s * 8;

    f32x4 acc[4] = {};

    float cy[2], cx[2], cm[2];
    #pragma unroll
    for (int h = 0; h < 2; ++h) {
        cy[h] = offB[pix0 + h * 8];
        cx[h] = offB[HW_ + pix0 + h * 8];
        cm[h] = mB[pix0 + h * 8];
    }

    {   // prologue: stage weights kk=0 into wl[0]
        const uint4v* g = (const uint4v*)(wsb + (size_t)t * 16);
        char* d = wl0 + t * 32;
        uint4v g0 = g[0], g1 = g[1];
        *(uint4v*)d = g0; *(uint4v*)(d + 16) = g1;
    }

    #pragma unroll 1
    for (int kk = 0; kk < KK_; ++kk) {
        const int cur = kk & 1, nxt = cur ^ 1;
        __syncthreads();

        // ---- geometry + corner loads (halo: no masks, const offsets) ----
        uint4v cor[2][4];
        float  w4[2][4];
        #pragma unroll
        for (int h = 0; h < 2; ++h) {
            int pixg = pix0 + h * 8;
            int ho = pixg / W_, wo = pixg % W_;
            float py  = (float)(ho - 1 + kk / 3) + cy[h];
            float pxf = (float)(wo - 1 + kk % 3) + cx[h];
            float y0f = floorf(py), x0f = floorf(pxf);
            float ly = py - y0f, lx = pxf - x0f;
            int y0 = min(max((int)y0f, -2), H_ + 1);   // halo-clamped
            int x0 = min(max((int)x0f, -2), W_ + 1);
            float hy = 1.f - ly, hx = 1.f - lx;
            float mvy = cm[h] * hy, mly = cm[h] * ly;
            w4[h][0] = mvy * hx; w4[h][1] = mvy * lx;
            w4[h][2] = mly * hx; w4[h][3] = mly * lx;
            const char* cb = (const char*)(xB +
                (size_t)((y0 + 2) * PW_ + (x0 + 2)) * C_);
            if constexpr (V == 1) {
                asm volatile("" :: "v"(cb));           // keep addr chain live
                uint4v k; k.x = k.y = k.z = k.w = 0x3f803f80u;
                cor[h][0] = k; cor[h][1] = k; cor[h][2] = k; cor[h][3] = k;
            } else {
                cor[h][0] = *(const uint4v*)(cb);
                cor[h][1] = *(const uint4v*)(cb + 128);
                cor[h][2] = *(const uint4v*)(cb + PW_ * C_ * 2);
                cor[h][3] = *(const uint4v*)(cb + PW_ * C_ * 2 + 128);
            }
        }

        // ---- stage weights kk+1 -> wl[nxt] ----
        if (kk + 1 < KK_) {
            const uint4v* g = (const uint4v*)(wsb + (size_t)(kk+1)*4096 + t*16);
            char* d = wl0 + nxt * 8192 + t * 32;
            uint4v g0 = g[0], g1 = g[1];
            *(uint4v*)d = g0; *(uint4v*)(d + 16) = g1;
        }
        // ---- coords prefetch kk+1 ----
        if (kk + 1 < KK_) {
            #pragma unroll
            for (int h = 0; h < 2; ++h) {
                cy[h] = offB[(size_t)(2*kk + 2) * HW_ + pix0 + h * 8];
                cx[h] = offB[(size_t)(2*kk + 3) * HW_ + pix0 + h * 8];
                cm[h] = mB[(size_t)(kk + 1) * HW_ + pix0 + h * 8];
            }
        }

        if constexpr (V == 2) {
            // consume loads, skip all post-load compute
            #pragma unroll
            for (int h = 0; h < 2; ++h)
                #pragma unroll
                for (int c = 0; c < 4; ++c)
                    asm volatile("" :: "v"(cor[h][c][0]), "v"(cor[h][c][1]),
                                       "v"(cor[h][c][2]), "v"(cor[h][c][3]));
            asm volatile("" :: "v"(w4[0][0]), "v"(w4[1][0]));
            continue;
        }

        // ---- lerp + pack + swizzled ds_write ----
        #pragma unroll
        for (int h = 0; h < 2; ++h) {
            float w00 = w4[h][0], w01 = w4[h][1];
            float w10 = w4[h][2], w11 = w4[h][3];
            uint4v pk4;
            #pragma unroll
            for (int j = 0; j < 4; ++j) {
                unsigned u0 = cor[h][0][j], u1 = cor[h][1][j];
                unsigned u2 = cor[h][2][j], u3 = cor[h][3][j];
                float lo = fmaf(bflo(u0), w00, fmaf(bflo(u1), w01,
                           fmaf(bflo(u2), w10, bflo(u3) * w11)));
                float hi = fmaf(bfhi(u0), w00, fmaf(bfhi(u1), w01,
                           fmaf(bfhi(u2), w10, bfhi(u3) * w11)));
                pk4[j] = packbf2(lo, hi);
            }
            int pxl = ph0 + h * 8;
            *(uint4v*)(stg + pxl * 128 + ((s * 16) ^ ((pxl & 7) << 4))) = pk4;
        }

        // ---- B-frags + A-frags + MFMA ----
        union { uint4v u; short8 s8; } b0, b1;
        b0.u = *(const uint4v*)(stg + lr*128 + ((lg*16     ) ^ ((lr & 7) << 4)));
        b1.u = *(const uint4v*)(stg + lr*128 + ((64 + lg*16) ^ ((lr & 7) << 4)));
        const char* wlc = wl0 + cur * 8192;
        #pragma unroll
        for (int ks = 0; ks < 2; ++ks)
            #pragma unroll
            for (int m = 0; m < 4; ++m) {
                short8 a = *(const short8*)(wlc +
                    (((ks*4 + lg) * 64 + m*16 + lr) << 4));
                acc[m] = __builtin_amdgcn_mfma_f32_16x16x32_bf16(
                             a, ks ? b1.s8 : b0.s8, acc[m], 0, 0, 0);
            }
    }

    // ---- epilogue ----
    __syncthreads();
    float* outb = (float*)lds;
    #pragma unroll
    for (int m = 0; m < 4; ++m)
        #pragma unroll
        for (int r = 0; r < 4; ++r)
            outb[(m * 16 + lg * 4 + r) * 68 + wid * 16 + lr] = acc[m][r];
    __syncthreads();
    #pragma unroll
    for (int r = 0; r < 4; ++r) {
        int idx = t + 256 * r;
        int o = idx >> 4, pq = (idx & 15) * 4;
        float4 v = *(const float4*)&outb[o * 68 + pq];
        float bv = bias[o];
        v.x += bv; v.y += bv; v.z += bv; v.w += bv;
        *(float4*)&out[((size_t)bi * O_ + o) * HW_ + pixbase + pq] = v;
    }
}

extern "C" void kernel_launch(void* const* d_in, const int* in_sizes, int n_in,
                              void* d_out, int out_size, void* d_ws, size_t ws_size,
                              hipStream_t stream)
{
    const float* x    = (const float*)d_in[0];
    const float* offs = (const float*)d_in[1];
    const float* mask = (const float*)d_in[2];
    const float* wgt  = (const float*)d_in[3];
    const float* bias = (const float*)d_in[4];
    float* out = (float*)d_out;

    unsigned short* xP  = (unsigned short*)d_ws;                      // 11,075,584 B
    unsigned short* wsb = (unsigned short*)((char*)d_ws + 11534336);  // 73,728 B
    float* scr1 = (float*)((char*)d_ws + 16777216);                   // V1 scratch
    float* scr2 = (float*)((char*)d_ws + 37748736);                   // V2 scratch

    hipLaunchKernelGGL(cvt_kernel, dim3(8 * 43), dim3(256), 0, stream,
                       x, wgt, xP, wsb);
    hipLaunchKernelGGL((dcn_mfma<0>), dim3(B_ * NTILE), dim3(256), 0, stream,
                       xP, offs, mask, wsb, bias, out);
    // ---- ablation probes (write scratch; rocprof separates their dur) ----
    hipLaunchKernelGGL((dcn_mfma<1>), dim3(B_ * NTILE), dim3(256), 0, stream,
                       xP, offs, mask, wsb, bias, scr1);
    hipLaunchKernelGGL((dcn_mfma<2>), dim3(B_ * NTILE), dim3(256), 0, stream,
                       xP, offs, mask, wsb, bias, scr2);
}

// Round 16
// 53.230 us; speedup vs baseline: 1.5531x; 1.5531x over previous
//
#include <hip/hip_runtime.h>
#include <hip/hip_bf16.h>

// DCNv2 fwd — R16: TLP round. R13-V0 wave structure (16px x 64o per wave,
// halo-padded gather, barrier-free main loop) in 128-thread blocks:
// grid 2304 (9 blocks/CU supply), launch_bounds(128,4) -> up to 16 waves/CU.
// R13 ablation showed gather(20us)+compute(20us) additive at 8 waves/CU;
// more resident waves interleave the serial chains.
// B=8, C=64, H=W=96, O=64, K=3, s=1, p=1, d=1, DG=1 -> Ho=Wo=96.

#define B_   8
#define C_   64
#define H_   96
#define W_   96
#define O_   64
#define KK_  9
#define HW_  (H_ * W_)          // 9216
#define NT32 (HW_ / 32)         // 288 tiles of 32 px
#define PW_  104                // padded width/height (halo: interior at +2)
#define PHW_ (PW_ * PW_)        // 10816
#define ROWB (PW_ * C_ * 2)     // padded row stride bytes = 13312

typedef __attribute__((ext_vector_type(8))) short short8;     // 8 bf16
typedef __attribute__((ext_vector_type(4))) float f32x4;
typedef __attribute__((ext_vector_type(4))) unsigned uint4v;

__device__ __forceinline__ unsigned short f2bf(float f) {
    union { float f; unsigned u; } v; v.f = f;
    unsigned r = v.u + 0x7FFF + ((v.u >> 16) & 1);   // RNE
    return (unsigned short)(r >> 16);
}
__device__ __forceinline__ float bflo(unsigned u) {
    union { unsigned u; float f; } v; v.u = u << 16; return v.f;
}
__device__ __forceinline__ float bfhi(unsigned u) {
    union { unsigned u; float f; } v; v.u = u & 0xffff0000u; return v.f;
}
__device__ __forceinline__ unsigned packbf2(float lo, float hi) {
    __hip_bfloat162 h = __float22bfloat162_rn(make_float2(lo, hi));
    union { __hip_bfloat162 h; unsigned u; } v; v.h = h; return v.u;
}

// ---- converter: x NCHW f32 -> PADDED NHWC bf16 (zero halo);
//      blocks 0..15 also emit fragment-ordered bf16 weights ----
__global__ __launch_bounds__(256)
void cvt_kernel(const float* __restrict__ x, const float* __restrict__ wgt,
                unsigned short* __restrict__ xP, unsigned short* __restrict__ wsb)
{
    const int t = threadIdx.x;
    if (blockIdx.x < 16) {
        int i = blockIdx.x * 256 + t;      // (o,c) over 4096
        int o = i >> 6, c = i & 63;
        int ks = c >> 5, hi = (c >> 3) & 3, j = c & 7;
        #pragma unroll
        for (int kk = 0; kk < KK_; ++kk)
            wsb[(size_t)(((kk*2 + ks)*4 + hi)*64 + o)*8 + j] =
                f2bf(wgt[(size_t)(o*64 + c)*KK_ + kk]);
    }
    const int b = blockIdx.x & 7;                  // XCD-pinned
    const int p = (blockIdx.x >> 3) * 256 + t;     // padded pixel id
    if (p >= PHW_) return;
    const int py = p / PW_, px = p % PW_;
    const bool interior = (py >= 2) & (py < 2 + H_) & (px >= 2) & (px < 2 + W_);
    const int sp = (py - 2) * W_ + (px - 2);
    const float* xs = x + (size_t)b * C_ * HW_ + sp;
    unsigned pk[32];
    #pragma unroll
    for (int c2 = 0; c2 < 32; ++c2)
        pk[c2] = interior ? packbf2(xs[(size_t)(2*c2) * HW_],
                                    xs[(size_t)(2*c2+1) * HW_]) : 0u;
    uint4v* dst = (uint4v*)(xP + ((size_t)b * PHW_ + p) * C_);
    #pragma unroll
    for (int j = 0; j < 8; ++j) {
        uint4v v;
        v.x = pk[4*j]; v.y = pk[4*j+1]; v.z = pk[4*j+2]; v.w = pk[4*j+3];
        dst[j] = v;
    }
}

// LDS: stg 2 waves x 2048 B ([16 px][128 B], XOR-swz), single-buffered
//      (per-wave in-order DS pipe makes WAR safe, no barrier needed).
//      Epilogue aliases [64 o][36 f32] = 9216 B after a 2-wave barrier.
__global__ __launch_bounds__(128, 4)
void dcn_mfma(const unsigned short* __restrict__ xP,
              const float* __restrict__ offs, const float* __restrict__ mask,
              const unsigned short* __restrict__ wsb,
              const float* __restrict__ bias, float* __restrict__ out)
{
    __shared__ __align__(16) char lds[9216];

    const int t    = threadIdx.x;
    const int lane = t & 63;
    const int wid  = t >> 6;                       // 0..1
    const int bi   = blockIdx.x & 7;               // XCD-pinned
    const int tile = blockIdx.x >> 3;              // 0..287
    const int pixbase = tile * 32;

    const int lr = lane & 15, lg = lane >> 4;      // MFMA fragment coords
    const int s   = lane & 7;                      // 16B slice within line
    const int ph0 = lane >> 3;                     // sample pixel (h=0); +8 h=1
    const int pix0 = pixbase + wid * 16 + ph0;

    const float* offB = offs + (size_t)bi * 18 * HW_;
    const float* mB   = mask + (size_t)bi * 9  * HW_;
    const unsigned short* xB = xP + (size_t)bi * PHW_ * C_ + s * 8;
    char* stg = lds + wid * 2048;                  // wave-private staging

    f32x4 acc[4] = {};                             // 4 o-tiles x (16o x 16px)

    // coords for current kk, both pixel halves
    float cy[2], cx[2], cm[2];
    #pragma unroll
    for (int h = 0; h < 2; ++h) {
        cy[h] = offB[pix0 + h * 8];
        cx[h] = offB[HW_ + pix0 + h * 8];
        cm[h] = mB[pix0 + h * 8];
    }

    #pragma unroll 1
    for (int kk = 0; kk < KK_; ++kk) {
        // ---- geometry + corner loads (halo: no masks, const offsets) ----
        uint4v cor[2][4];
        float  w4[2][4];
        #pragma unroll
        for (int h = 0; h < 2; ++h) {
            int pixg = pix0 + h * 8;
            int ho = pixg / W_, wo = pixg % W_;
            float py  = (float)(ho - 1 + kk / 3) + cy[h];
            float pxf = (float)(wo - 1 + kk % 3) + cx[h];
            float y0f = floorf(py), x0f = floorf(pxf);
            float ly = py - y0f, lx = pxf - x0f;
            int y0 = min(max((int)y0f, -2), H_ + 1);   // halo-clamped
            int x0 = min(max((int)x0f, -2), W_ + 1);
            float hy = 1.f - ly, hx = 1.f - lx;
            float a = cm[h] * hy, b2 = cm[h] * ly;
            w4[h][0] = a * hx;  w4[h][1] = a * lx;
            w4[h][2] = b2 * hx; w4[h][3] = b2 * lx;
            const char* cb = (const char*)(xB +
                (size_t)((y0 + 2) * PW_ + (x0 + 2)) * C_);
            cor[h][0] = *(const uint4v*)(cb);
            cor[h][1] = *(const uint4v*)(cb + 128);
            cor[h][2] = *(const uint4v*)(cb + ROWB);
            cor[h][3] = *(const uint4v*)(cb + ROWB + 128);
        }

        // ---- A-frags(kk) from fragment-ordered global (L1/L2-hot) ----
        short8 af[8];
        #pragma unroll
        for (int ks = 0; ks < 2; ++ks)
            #pragma unroll
            for (int m = 0; m < 4; ++m)
                af[ks*4 + m] = *(const short8*)(wsb +
                    (size_t)((((kk*2 + ks)*4 + lg)*64) + m*16 + lr) * 8);

        // ---- coords prefetch kk+1 ----
        if (kk + 1 < KK_) {
            #pragma unroll
            for (int h = 0; h < 2; ++h) {
                cy[h] = offB[(size_t)(2*kk + 2) * HW_ + pix0 + h * 8];
                cx[h] = offB[(size_t)(2*kk + 3) * HW_ + pix0 + h * 8];
                cm[h] = mB[(size_t)(kk + 1) * HW_ + pix0 + h * 8];
            }
        }

        // ---- lerp (lane-local slice) + pack + swizzled ds_write ----
        #pragma unroll
        for (int h = 0; h < 2; ++h) {
            float w00 = w4[h][0], w01 = w4[h][1];
            float w10 = w4[h][2], w11 = w4[h][3];
            uint4v pk4;
            #pragma unroll
            for (int j = 0; j < 4; ++j) {
                unsigned u0 = cor[h][0][j], u1 = cor[h][1][j];
                unsigned u2 = cor[h][2][j], u3 = cor[h][3][j];
                float lo = fmaf(bflo(u0), w00, fmaf(bflo(u1), w01,
                           fmaf(bflo(u2), w10, bflo(u3) * w11)));
                float hi = fmaf(bfhi(u0), w00, fmaf(bfhi(u1), w01,
                           fmaf(bfhi(u2), w10, bfhi(u3) * w11)));
                pk4[j] = packbf2(lo, hi);
            }
            int pxl = ph0 + h * 8;
            *(uint4v*)(stg + pxl * 128 + ((s * 16) ^ ((pxl & 7) << 4))) = pk4;
        }

        // ---- B-frags (own-wave LDS, in-order DS pipe) + MFMA ----
        union { uint4v u; short8 s8; } b0, b1;
        b0.u = *(const uint4v*)(stg + lr*128 + ((lg*16     ) ^ ((lr & 7) << 4)));
        b1.u = *(const uint4v*)(stg + lr*128 + ((64 + lg*16) ^ ((lr & 7) << 4)));
        #pragma unroll
        for (int m = 0; m < 4; ++m)
            acc[m] = __builtin_amdgcn_mfma_f32_16x16x32_bf16(af[m],     b0.s8, acc[m], 0, 0, 0);
        #pragma unroll
        for (int m = 0; m < 4; ++m)
            acc[m] = __builtin_amdgcn_mfma_f32_16x16x32_bf16(af[4 + m], b1.s8, acc[m], 0, 0, 0);
    }

    // ---- epilogue: LDS transpose -> full-128B-line coalesced stores ----
    __syncthreads();                 // both waves done with stg before alias
    float* outb = (float*)lds;       // [64 o][36 f32] (144 B rows, 16B-aligned)
    #pragma unroll
    for (int m = 0; m < 4; ++m)
        #pragma unroll
        for (int r = 0; r < 4; ++r)
            outb[(m * 16 + lg * 4 + r) * 36 + wid * 16 + lr] = acc[m][r];
    __syncthreads();
    #pragma unroll
    for (int r = 0; r < 4; ++r) {
        int idx = t + 128 * r;       // 512 float4 chunks (64o x 32px)
        int o = idx >> 3, c = idx & 7;
        float4 v = *(const float4*)&outb[o * 36 + c * 4];
        float bv = bias[o];
        v.x += bv; v.y += bv; v.z += bv; v.w += bv;
        *(float4*)&out[((size_t)bi * O_ + o) * HW_ + pixbase + c * 4] = v;
    }
}

extern "C" void kernel_launch(void* const* d_in, const int* in_sizes, int n_in,
                              void* d_out, int out_size, void* d_ws, size_t ws_size,
                              hipStream_t stream)
{
    const float* x    = (const float*)d_in[0];
    const float* offs = (const float*)d_in[1];
    const float* mask = (const float*)d_in[2];
    const float* wgt  = (const float*)d_in[3];
    const float* bias = (const float*)d_in[4];
    float* out = (float*)d_out;

    unsigned short* xP  = (unsigned short*)d_ws;                      // 11,075,584 B
    unsigned short* wsb = (unsigned short*)((char*)d_ws + 11534336);  // 73,728 B

    hipLaunchKernelGGL(cvt_kernel, dim3(8 * 43), dim3(256), 0, stream,
                       x, wgt, xP, wsb);
    hipLaunchKernelGGL(dcn_mfma, dim3(8 * NT32), dim3(128), 0, stream,
                       xP, offs, mask, wsb, bias, out);
}